// Round 7
// baseline (51388.861 us; speedup 1.0000x reference)
//
#include <hip/hip_runtime.h>

// Problem constants
#define Hh   512
#define Vv   128
#define LL   8192
#define G3   1536      // 3*H
#define NBK  256       // seq2 blocks: one wave each, owns 2 h0 + 2 h1 elements
#define NPAIR 1024     // pairs per record slot: h0[512] ++ h1[512]

// workspace layout (bytes)
#define OFF_GX   0ull                       // 8192*1536*4 = 50,331,648
#define OFF_YS   50331648ull                // 8192*512*4  = 16,777,216
#define OFF_RECE 67108864ull                // 2*1024*8    = 16,384
#define OFF_RECD (OFF_RECE + 16384ull)      // 16,384
#define OFF_WT   (OFF_RECD + 16384ull)      // 512*128*4   = 262,144

__device__ __forceinline__ float sigm(float x)  { return 1.f / (1.f + __expf(-x)); }
__device__ __forceinline__ float tanha(float x) { return 2.f / (1.f + __expf(-2.f * x)) - 1.f; }

__device__ __forceinline__ unsigned long long packpair(float v, int t) {
    return ((unsigned long long)(unsigned)t << 32) | (unsigned long long)__float_as_uint(v);
}
__device__ __forceinline__ int   pair_tag(unsigned long long p) { return (int)(p >> 32); }
__device__ __forceinline__ float pair_val(unsigned long long p) { return __uint_as_float((unsigned)p); }

// DPP add: m += lane-permuted(m). CTRL: 0xB1 = quad_perm(1,0,3,2) (xor1),
// 0x122/0x124/0x128 = row_ror:2/4/8 (parity-preserving ring steps within 16).
template <int CTRL>
__device__ __forceinline__ float dpp_add(float m) {
    int t = __builtin_amdgcn_update_dpp(0, __builtin_bit_cast(int, m), CTRL, 0xF, 0xF, true);
    return m + __builtin_bit_cast(float, t);
}

// ---------------------------------------------------------------------------
// gx = X @ Wih^T + bih  (layer-0 input pre-activations, fully parallel)
// ---------------------------------------------------------------------------
__global__ __launch_bounds__(256) void gemm_gx(
    const float* __restrict__ X, const float* __restrict__ Wih,
    const float* __restrict__ bih, float* __restrict__ gxo, int shift_relu)
{
    __shared__ float xs[16][128];
    const int tid = threadIdx.x;
    const int m0  = blockIdx.x * 16;
    const int c   = blockIdx.y * 256 + tid;   // 0..1535 (row of Wih)

    for (int i = tid; i < 16 * 128; i += 256) {
        const int r = i >> 7, k = i & 127;
        int srow = m0 + r;
        if (shift_relu) srow = (srow == 0) ? 0 : (srow - 1);
        float v = X[(size_t)srow * Vv + k];
        if (shift_relu) v = fmaxf(v, 0.f);
        xs[r][k] = v;
    }
    __syncthreads();

    const float4* wp = (const float4*)(Wih + (size_t)c * Vv);
    float4 wr[32];
#pragma unroll
    for (int q = 0; q < 32; ++q) wr[q] = wp[q];
    const float bb = bih[c];

    for (int m = 0; m < 16; ++m) {
        const float4* xp = (const float4*)xs[m];
        float acc = bb;
#pragma unroll
        for (int q = 0; q < 32; ++q) {
            const float4 x4 = xp[q];
            acc = fmaf(wr[q].x, x4.x, acc); acc = fmaf(wr[q].y, x4.y, acc);
            acc = fmaf(wr[q].z, x4.z, acc); acc = fmaf(wr[q].w, x4.w, acc);
        }
        gxo[(size_t)(m0 + m) * G3 + c] = acc;
    }
}

// ---------------------------------------------------------------------------
// Persistent 2-layer GRU scan: 256 blocks x 1 wave, weights AGPR-pinned.
// Record tau = { h0(tau), h1(tau-1) } as (value,tag) pairs, 2-slot ring.
// TWO-PHASE DETECT: (1) spin on 4 representative pairs per lane (one per
// publishing store instruction: rec[2b] and rec[512+2b] for blocks b=2*lane,
// 2*lane+1) -> 8x less spin traffic on the hot LLC lines; (2) one bulk load
// of all 16 pairs/lane + full tag revalidation (correctness never assumes a
// rep implies its neighbors; rare straggler -> bulk retry).
// ---------------------------------------------------------------------------
__global__ __launch_bounds__(64, 1) void seq2(
    const float* __restrict__ gx,
    const float* __restrict__ Whh0, const float* __restrict__ Wih1,
    const float* __restrict__ Whh1,
    const float* __restrict__ bhh0, const float* __restrict__ bih1,
    const float* __restrict__ bhh1,
    unsigned long long* __restrict__ rec,
    float* __restrict__ ys)
{
    const int bid  = blockIdx.x, lane = threadIdx.x;
    const int e0   = 2 * bid;

    // rotated per-lane K offsets: element e0+i lands in lane i, reg 0
    int off[8];
#pragma unroll
    for (int j = 0; j < 8; ++j) off[j] = (e0 + lane + 64 * j) & 511;

    // one-time: stage 18 weight rows into registers (row r = m*6 + g*2 + i)
    float wv[18][8];
#pragma unroll
    for (int m = 0; m < 3; ++m) {
        const float* mat = (m == 0) ? Whh0 : (m == 1) ? Wih1 : Whh1;
#pragma unroll
        for (int g = 0; g < 3; ++g)
#pragma unroll
            for (int i = 0; i < 2; ++i) {
                const float* row = mat + (size_t)(g * Hh + e0 + i) * Hh;
#pragma unroll
                for (int j = 0; j < 8; ++j) wv[m * 6 + g * 2 + i][j] = row[off[j]];
            }
    }
    // pin all 144 weights into AGPRs (separate file; not remat-able)
#pragma unroll
    for (int r = 0; r < 18; ++r)
#pragma unroll
        for (int j = 0; j < 8; ++j)
            asm volatile("" : "+a"(wv[r][j]));

    // biases: lanes 0,1 = layer0 elem e0+lane; lanes 2,3 = layer1 elem e0+(lane&1)
    float b_r = 0.f, b_z = 0.f, b_n1 = 0.f, b_n2 = 0.f;
    if (lane < 2) {
        const int e = e0 + lane;
        b_r = bhh0[e]; b_z = bhh0[Hh + e]; b_n1 = bhh0[2 * Hh + e];
    } else if (lane < 4) {
        const int e = e0 + (lane & 1);
        b_r  = bih1[e] + bhh1[e];
        b_z  = bih1[Hh + e] + bhh1[Hh + e];
        b_n1 = bih1[2 * Hh + e];      // x-side n bias
        b_n2 = bhh1[2 * Hh + e];      // h-side n bias (inside r*(.))
    }

    // representative pair indices for the cheap spin (blocks 2*lane, 2*lane+1)
    const int r0 = 4 * lane;          // rec[2b] for b = 2*lane
    const int r1 = 4 * lane + 2;      // rec[2b] for b = 2*lane+1

    for (int tau = 0; tau <= LL; ++tau) {
        // prefetch gx row early (latency hides under the poll)
        float xr = 0.f, xz = 0.f, xn = 0.f;
        if (lane < 2 && tau < LL) {
            const size_t gb = (size_t)tau * G3 + e0 + lane;
            xr = gx[gb]; xz = gx[gb + Hh]; xn = gx[gb + 2 * Hh];
        }

        const int need = tau - 1;
        const unsigned long long* rp = rec + (size_t)((tau - 1) & 1) * NPAIR;

        // phase 1: representative spin (4 pairs/lane, 2KB/wave/round)
        {
            int ok;
            do {
                const unsigned long long a = __hip_atomic_load(rp + r0,      __ATOMIC_RELAXED, __HIP_MEMORY_SCOPE_AGENT);
                const unsigned long long b = __hip_atomic_load(rp + r1,      __ATOMIC_RELAXED, __HIP_MEMORY_SCOPE_AGENT);
                const unsigned long long c = __hip_atomic_load(rp + Hh + r0, __ATOMIC_RELAXED, __HIP_MEMORY_SCOPE_AGENT);
                const unsigned long long d = __hip_atomic_load(rp + Hh + r1, __ATOMIC_RELAXED, __HIP_MEMORY_SCOPE_AGENT);
                ok = (pair_tag(a) >= need) & (pair_tag(b) >= need) &
                     (pair_tag(c) >= need) & (pair_tag(d) >= need);
            } while (!__all(ok));
        }

        // phase 2: bulk load + full revalidation (rare retry)
        unsigned long long p0[8], p1[8];
        for (;;) {
#pragma unroll
            for (int j = 0; j < 8; ++j)
                p0[j] = __hip_atomic_load(rp + off[j],      __ATOMIC_RELAXED, __HIP_MEMORY_SCOPE_AGENT);
#pragma unroll
            for (int j = 0; j < 8; ++j)
                p1[j] = __hip_atomic_load(rp + Hh + off[j], __ATOMIC_RELAXED, __HIP_MEMORY_SCOPE_AGENT);
            int ok = 1;
#pragma unroll
            for (int j = 0; j < 8; ++j)
                ok &= (pair_tag(p0[j]) >= need) & (pair_tag(p1[j]) >= need);
            if (__all(ok)) break;
        }

        float h0v[8], h1v[8];
#pragma unroll
        for (int j = 0; j < 8; ++j) { h0v[j] = pair_val(p0[j]); h1v[j] = pair_val(p1[j]); }

        // keep weights AGPR-classed across the loop (prevents hoisted copies)
#pragma unroll
        for (int r = 0; r < 18; ++r)
#pragma unroll
            for (int j = 0; j < 8; ++j)
                asm volatile("" : "+a"(wv[r][j]));

        // 18 register dots: rows 0..11 @ h0(tau-1), rows 12..17 @ h1(tau-2)
        float acc[18];
#pragma unroll
        for (int r = 0; r < 18; ++r) acc[r] = 0.f;
#pragma unroll
        for (int j = 0; j < 8; ++j) {
#pragma unroll
            for (int r = 0; r < 12; ++r) acc[r] = fmaf(wv[r][j], h0v[j], acc[r]);
#pragma unroll
            for (int r = 12; r < 18; ++r) acc[r] = fmaf(wv[r][j], h1v[j], acc[r]);
        }

        // pair-merged butterfly, DPP levels: sred[k] = row-2k sum on even
        // lanes / row-2k+1 on odd.
        float sred[9];
#pragma unroll
        for (int k = 0; k < 9; ++k) {
            float a = dpp_add<0xB1>(acc[2 * k]);
            float c = dpp_add<0xB1>(acc[2 * k + 1]);
            float m = (lane & 1) ? c : a;
            m = dpp_add<0x122>(m);   // row_ror:2
            m = dpp_add<0x124>(m);   // row_ror:4
            m = dpp_add<0x128>(m);   // row_ror:8
            m += __shfl_xor(m, 16);
            m += __shfl_xor(m, 32);
            sred[k] = m;
        }

        // h1prev[e0+(lane&1)] for lanes 2,3 (source lanes 0,1 hold it in reg 0)
        const float h1p = __shfl(h1v[0], lane & 1);

        unsigned long long* recw = rec + (size_t)(tau & 1) * NPAIR;
        if (lane < 2) {
            if (tau < LL) {   // layer 0, element e0+lane; h0prev local in h0v[0]
                const float rg = sigm(xr + sred[0] + b_r);
                const float zg = sigm(xz + sred[1] + b_z);
                const float ng = tanha(xn + rg * (sred[2] + b_n1));
                const float hnew = (1.f - zg) * ng + zg * h0v[0];
                __hip_atomic_store(recw + e0 + lane, packpair(hnew, tau),
                                   __ATOMIC_RELAXED, __HIP_MEMORY_SCOPE_AGENT);
            }
        } else if (lane < 4) { // layer 1, element e0+(lane&1), step tau-1
            const int e = e0 + (lane & 1);
            float hnew;
            if (tau >= 1) {
                const float rg = sigm(sred[3] + sred[6] + b_r);
                const float zg = sigm(sred[4] + sred[7] + b_z);
                const float ng = tanha(sred[5] + b_n1 + rg * (sred[8] + b_n2));
                hnew = (1.f - zg) * ng + zg * h1p;
                if (ys) ys[(size_t)(tau - 1) * Hh + e] = hnew;
            } else {
                hnew = h1p;   // pass initial h1 through as "h1(-1)"
            }
            __hip_atomic_store(recw + Hh + e, packpair(hnew, tau),
                               __ATOMIC_RELAXED, __HIP_MEMORY_SCOPE_AGENT);
        }
    }
}

// ---------------------------------------------------------------------------
// WoutT + encoder record init (slot1: h=0 tag=-1; slot0: tag=-2)
// ---------------------------------------------------------------------------
__global__ __launch_bounds__(256) void transposeW(const float* __restrict__ W,
                                                  float* __restrict__ WT,
                                                  unsigned long long* __restrict__ encr)
{
    const int i = blockIdx.x * 256 + threadIdx.x;  // 0..65535
    WT[(i & 511) * 128 + (i >> 9)] = W[i];
    if (i < NPAIR) {
        __hip_atomic_store(encr + NPAIR + i, packpair(0.f, -1),
                           __ATOMIC_RELAXED, __HIP_MEMORY_SCOPE_AGENT);
        __hip_atomic_store(encr + i, packpair(0.f, -2),
                           __ATOMIC_RELAXED, __HIP_MEMORY_SCOPE_AGENT);
    }
}

// ---------------------------------------------------------------------------
// encoder -> decoder handoff. enc h0(L-1): slot1 pairs [0..511] (tick L-1);
// enc h1(L-1): slot0 pairs [512..1023] (tick L). dec slot1 tag=-1, slot0 tag=-2.
// ---------------------------------------------------------------------------
__global__ __launch_bounds__(256) void handoff(const unsigned long long* __restrict__ encr,
                                               unsigned long long* __restrict__ decr)
{
    const int p = blockIdx.x * 256 + threadIdx.x;  // 0..1023
    const unsigned long long src = __hip_atomic_load(
        encr + (p < Hh ? NPAIR : 0) + p, __ATOMIC_RELAXED, __HIP_MEMORY_SCOPE_AGENT);
    __hip_atomic_store(decr + NPAIR + p, packpair(pair_val(src), -1),
                       __ATOMIC_RELAXED, __HIP_MEMORY_SCOPE_AGENT);
    __hip_atomic_store(decr + p, packpair(0.f, -2),
                       __ATOMIC_RELAXED, __HIP_MEMORY_SCOPE_AGENT);
}

// ---------------------------------------------------------------------------
// out = sigmoid(ys @ Wout^T + bout)
// ---------------------------------------------------------------------------
__global__ __launch_bounds__(128) void out_proj(
    const float* __restrict__ ys, const float* __restrict__ WT,
    const float* __restrict__ bout, float* __restrict__ out)
{
    __shared__ float yss[16][512];
    const int tid = threadIdx.x;
    const int m0  = blockIdx.x * 16;

    for (int i = tid; i < 16 * 512; i += 128)
        yss[i >> 9][i & 511] = ys[(size_t)(m0 + (i >> 9)) * 512 + (i & 511)];
    __syncthreads();

    const int c = tid;  // 0..127
    float acc[16];
    const float b = bout[c];
#pragma unroll
    for (int m = 0; m < 16; ++m) acc[m] = b;

    for (int k4 = 0; k4 < 128; ++k4) {
        const float w0 = WT[(4 * k4 + 0) * 128 + c];
        const float w1 = WT[(4 * k4 + 1) * 128 + c];
        const float w2 = WT[(4 * k4 + 2) * 128 + c];
        const float w3 = WT[(4 * k4 + 3) * 128 + c];
#pragma unroll
        for (int m = 0; m < 16; ++m) {
            const float4 yv = *(const float4*)&yss[m][4 * k4];
            acc[m] = fmaf(w0, yv.x, fmaf(w1, yv.y, fmaf(w2, yv.z, fmaf(w3, yv.w, acc[m]))));
        }
    }
#pragma unroll
    for (int m = 0; m < 16; ++m)
        out[(size_t)(m0 + m) * 128 + c] = 1.f / (1.f + __expf(-acc[m]));
}

// ---------------------------------------------------------------------------
extern "C" void kernel_launch(void* const* d_in, const int* in_sizes, int n_in,
                              void* d_out, int out_size, void* d_ws, size_t ws_size,
                              hipStream_t stream)
{
    const float* src      = (const float*)d_in[0];
    const float* trg      = (const float*)d_in[1];
    const float* eWih0    = (const float*)d_in[2];
    const float* eWhh0    = (const float*)d_in[3];
    const float* ebih0    = (const float*)d_in[4];
    const float* ebhh0    = (const float*)d_in[5];
    const float* eWih1    = (const float*)d_in[6];
    const float* eWhh1    = (const float*)d_in[7];
    const float* ebih1    = (const float*)d_in[8];
    const float* ebhh1    = (const float*)d_in[9];
    const float* dWih0    = (const float*)d_in[10];
    const float* dWhh0    = (const float*)d_in[11];
    const float* dbih0    = (const float*)d_in[12];
    const float* dbhh0    = (const float*)d_in[13];
    const float* dWih1    = (const float*)d_in[14];
    const float* dWhh1    = (const float*)d_in[15];
    const float* dbih1    = (const float*)d_in[16];
    const float* dbhh1    = (const float*)d_in[17];
    const float* Wout     = (const float*)d_in[18];
    const float* bout     = (const float*)d_in[19];

    char* ws = (char*)d_ws;
    float*              gx   = (float*)(ws + OFF_GX);
    float*              ys   = (float*)(ws + OFF_YS);
    unsigned long long* recE = (unsigned long long*)(ws + OFF_RECE);
    unsigned long long* recD = (unsigned long long*)(ws + OFF_RECD);
    float*              WT   = (float*)(ws + OFF_WT);

    hipLaunchKernelGGL(transposeW, dim3(256), dim3(256), 0, stream, Wout, WT, recE);

    // ---- encoder ----
    hipLaunchKernelGGL(gemm_gx, dim3(LL / 16, 6), dim3(256), 0, stream,
                       src, eWih0, ebih0, gx, 0);
    hipLaunchKernelGGL(seq2, dim3(NBK), dim3(64), 0, stream,
                       gx, eWhh0, eWih1, eWhh1, ebhh0, ebih1, ebhh1,
                       recE, (float*)nullptr);

    // ---- handoff + decoder ----
    hipLaunchKernelGGL(handoff, dim3(4), dim3(256), 0, stream, recE, recD);
    hipLaunchKernelGGL(gemm_gx, dim3(LL / 16, 6), dim3(256), 0, stream,
                       trg, dWih0, dbih0, gx, 1);
    hipLaunchKernelGGL(seq2, dim3(NBK), dim3(64), 0, stream,
                       gx, dWhh0, dWih1, dWhh1, dbhh0, dbih1, dbhh1,
                       recD, ys);

    // ---- output projection ----
    hipLaunchKernelGGL(out_proj, dim3(LL / 16), dim3(128), 0, stream,
                       ys, WT, bout, (float*)d_out);

    (void)in_sizes; (void)n_in; (void)out_size; (void)ws_size;
}

// Round 8
// 34287.991 us; speedup vs baseline: 1.4987x; 1.4987x over previous
//
#include <hip/hip_runtime.h>

// Problem constants
#define Hh   512
#define Vv   128
#define LL   8192
#define G3   1536      // 3*H
#define NBK  256       // seq2 blocks: one wave each, owns 2 h0 + 2 h1 elements
#define NPAIR 1024     // pairs per record slot: h0[512] ++ h1[512]
#define NREP 8         // record replicas (poll-traffic spreading)
#define RSTR (2*NPAIR) // pairs per replica (2 slots)

// workspace layout (bytes)
#define OFF_GX   0ull                       // 8192*1536*4 = 50,331,648
#define OFF_YS   50331648ull                // 8192*512*4  = 16,777,216
#define OFF_RECE 67108864ull                // 8 rep * 2 slot * 1024 * 8 = 131,072
#define OFF_RECD (OFF_RECE + 131072ull)     // 131,072
#define OFF_WT   (OFF_RECD + 131072ull)     // 512*128*4 = 262,144

__device__ __forceinline__ float sigm(float x)  { return 1.f / (1.f + __expf(-x)); }
__device__ __forceinline__ float tanha(float x) { return 2.f / (1.f + __expf(-2.f * x)) - 1.f; }

__device__ __forceinline__ unsigned long long packpair(float v, int t) {
    return ((unsigned long long)(unsigned)t << 32) | (unsigned long long)__float_as_uint(v);
}
__device__ __forceinline__ int   pair_tag(unsigned long long p) { return (int)(p >> 32); }
__device__ __forceinline__ float pair_val(unsigned long long p) { return __uint_as_float((unsigned)p); }

// DPP add: m += lane-permuted(m). CTRL: 0xB1 = quad_perm(1,0,3,2) (xor1),
// 0x122/0x124/0x128 = row_ror:2/4/8 (parity-preserving ring steps within 16).
template <int CTRL>
__device__ __forceinline__ float dpp_add(float m) {
    int t = __builtin_amdgcn_update_dpp(0, __builtin_bit_cast(int, m), CTRL, 0xF, 0xF, true);
    return m + __builtin_bit_cast(float, t);
}

// ---------------------------------------------------------------------------
// gx = X @ Wih^T + bih  (layer-0 input pre-activations, fully parallel)
// ---------------------------------------------------------------------------
__global__ __launch_bounds__(256) void gemm_gx(
    const float* __restrict__ X, const float* __restrict__ Wih,
    const float* __restrict__ bih, float* __restrict__ gxo, int shift_relu)
{
    __shared__ float xs[16][128];
    const int tid = threadIdx.x;
    const int m0  = blockIdx.x * 16;
    const int c   = blockIdx.y * 256 + tid;   // 0..1535 (row of Wih)

    for (int i = tid; i < 16 * 128; i += 256) {
        const int r = i >> 7, k = i & 127;
        int srow = m0 + r;
        if (shift_relu) srow = (srow == 0) ? 0 : (srow - 1);
        float v = X[(size_t)srow * Vv + k];
        if (shift_relu) v = fmaxf(v, 0.f);
        xs[r][k] = v;
    }
    __syncthreads();

    const float4* wp = (const float4*)(Wih + (size_t)c * Vv);
    float4 wr[32];
#pragma unroll
    for (int q = 0; q < 32; ++q) wr[q] = wp[q];
    const float bb = bih[c];

    for (int m = 0; m < 16; ++m) {
        const float4* xp = (const float4*)xs[m];
        float acc = bb;
#pragma unroll
        for (int q = 0; q < 32; ++q) {
            const float4 x4 = xp[q];
            acc = fmaf(wr[q].x, x4.x, acc); acc = fmaf(wr[q].y, x4.y, acc);
            acc = fmaf(wr[q].z, x4.z, acc); acc = fmaf(wr[q].w, x4.w, acc);
        }
        gxo[(size_t)(m0 + m) * G3 + c] = acc;
    }
}

// ---------------------------------------------------------------------------
// Persistent 2-layer GRU scan: 256 blocks x 1 wave, weights AGPR-pinned.
// Record tau = { h0(tau), h1(tau-1) } as (value,tag) pairs, 2-slot ring,
// REPLICATED 8x: publishers store to all replicas; wave polls only replica
// bid&7 -> 8x fewer concurrent readers per LLC line, 8x address spread.
// Detect = data (single-phase poll, round-3/6 protocol). gx prefetched one
// tick ahead so the first poll round never waits on a fresh gx miss.
// ---------------------------------------------------------------------------
__global__ __launch_bounds__(64, 1) void seq2(
    const float* __restrict__ gx,
    const float* __restrict__ Whh0, const float* __restrict__ Wih1,
    const float* __restrict__ Whh1,
    const float* __restrict__ bhh0, const float* __restrict__ bih1,
    const float* __restrict__ bhh1,
    unsigned long long* __restrict__ rec,
    float* __restrict__ ys)
{
    const int bid  = blockIdx.x, lane = threadIdx.x;
    const int e0   = 2 * bid;
    const unsigned long long* myrep = rec + (size_t)(bid & 7) * RSTR;

    // rotated per-lane K offsets: element e0+i lands in lane i, reg 0
    int off[8];
#pragma unroll
    for (int j = 0; j < 8; ++j) off[j] = (e0 + lane + 64 * j) & 511;

    // one-time: stage 18 weight rows into registers (row r = m*6 + g*2 + i)
    float wv[18][8];
#pragma unroll
    for (int m = 0; m < 3; ++m) {
        const float* mat = (m == 0) ? Whh0 : (m == 1) ? Wih1 : Whh1;
#pragma unroll
        for (int g = 0; g < 3; ++g)
#pragma unroll
            for (int i = 0; i < 2; ++i) {
                const float* row = mat + (size_t)(g * Hh + e0 + i) * Hh;
#pragma unroll
                for (int j = 0; j < 8; ++j) wv[m * 6 + g * 2 + i][j] = row[off[j]];
            }
    }
    // pin all 144 weights into AGPRs (separate file; not remat-able)
#pragma unroll
    for (int r = 0; r < 18; ++r)
#pragma unroll
        for (int j = 0; j < 8; ++j)
            asm volatile("" : "+a"(wv[r][j]));

    // biases: lanes 0,1 = layer0 elem e0+lane; lanes 2,3 = layer1 elem e0+(lane&1)
    float b_r = 0.f, b_z = 0.f, b_n1 = 0.f, b_n2 = 0.f;
    if (lane < 2) {
        const int e = e0 + lane;
        b_r = bhh0[e]; b_z = bhh0[Hh + e]; b_n1 = bhh0[2 * Hh + e];
    } else if (lane < 4) {
        const int e = e0 + (lane & 1);
        b_r  = bih1[e] + bhh1[e];
        b_z  = bih1[Hh + e] + bhh1[Hh + e];
        b_n1 = bih1[2 * Hh + e];      // x-side n bias
        b_n2 = bhh1[2 * Hh + e];      // h-side n bias (inside r*(.))
    }

    // gx for tick 0 (prefetched; steady-state loads issue one tick ahead)
    float xr = 0.f, xz = 0.f, xn = 0.f;
    if (lane < 2) {
        const size_t gb = (size_t)0 * G3 + e0 + lane;
        xr = gx[gb]; xz = gx[gb + Hh]; xn = gx[gb + 2 * Hh];
    }

    for (int tau = 0; tau <= LL; ++tau) {
        // single-phase poll of record tau-1 in OWN replica (detect = data)
        const int need = tau - 1;
        const unsigned long long* rp = myrep + (size_t)((tau - 1) & 1) * NPAIR;
        unsigned long long p0[8], p1[8];
        int ok;
        do {
#pragma unroll
            for (int j = 0; j < 8; ++j)
                p0[j] = __hip_atomic_load(rp + off[j],      __ATOMIC_RELAXED, __HIP_MEMORY_SCOPE_AGENT);
#pragma unroll
            for (int j = 0; j < 8; ++j)
                p1[j] = __hip_atomic_load(rp + Hh + off[j], __ATOMIC_RELAXED, __HIP_MEMORY_SCOPE_AGENT);
            ok = 1;
#pragma unroll
            for (int j = 0; j < 8; ++j)
                ok &= (pair_tag(p0[j]) >= need) & (pair_tag(p1[j]) >= need);
        } while (!__all(ok));

        // prefetch NEXT tick's gx row now: latency hides under compute +
        // publish + next detect (~2000cy), so next tick's first poll round
        // never waits on it.
        float nxr = 0.f, nxz = 0.f, nxn = 0.f;
        if (lane < 2 && tau + 1 < LL) {
            const size_t gb = (size_t)(tau + 1) * G3 + e0 + lane;
            nxr = gx[gb]; nxz = gx[gb + Hh]; nxn = gx[gb + 2 * Hh];
        }

        float h0v[8], h1v[8];
#pragma unroll
        for (int j = 0; j < 8; ++j) { h0v[j] = pair_val(p0[j]); h1v[j] = pair_val(p1[j]); }

        // keep weights AGPR-classed across the loop (prevents hoisted copies)
#pragma unroll
        for (int r = 0; r < 18; ++r)
#pragma unroll
            for (int j = 0; j < 8; ++j)
                asm volatile("" : "+a"(wv[r][j]));

        // 18 register dots: rows 0..11 @ h0(tau-1), rows 12..17 @ h1(tau-2)
        float acc[18];
#pragma unroll
        for (int r = 0; r < 18; ++r) acc[r] = 0.f;
#pragma unroll
        for (int j = 0; j < 8; ++j) {
#pragma unroll
            for (int r = 0; r < 12; ++r) acc[r] = fmaf(wv[r][j], h0v[j], acc[r]);
#pragma unroll
            for (int r = 12; r < 18; ++r) acc[r] = fmaf(wv[r][j], h1v[j], acc[r]);
        }

        // pair-merged butterfly, DPP levels: sred[k] = row-2k sum on even
        // lanes / row-2k+1 on odd.
        float sred[9];
#pragma unroll
        for (int k = 0; k < 9; ++k) {
            float a = dpp_add<0xB1>(acc[2 * k]);
            float c = dpp_add<0xB1>(acc[2 * k + 1]);
            float m = (lane & 1) ? c : a;
            m = dpp_add<0x122>(m);   // row_ror:2
            m = dpp_add<0x124>(m);   // row_ror:4
            m = dpp_add<0x128>(m);   // row_ror:8
            m += __shfl_xor(m, 16);
            m += __shfl_xor(m, 32);
            sred[k] = m;
        }

        // h1prev[e0+(lane&1)] for lanes 2,3 (source lanes 0,1 hold it in reg 0)
        const float h1p = __shfl(h1v[0], lane & 1);

        const size_t slotoff = (size_t)(tau & 1) * NPAIR;
        if (lane < 2) {
            if (tau < LL) {   // layer 0, element e0+lane; h0prev local in h0v[0]
                const float rg = sigm(xr + sred[0] + b_r);
                const float zg = sigm(xz + sred[1] + b_z);
                const float ng = tanha(xn + rg * (sred[2] + b_n1));
                const float hnew = (1.f - zg) * ng + zg * h0v[0];
                const unsigned long long pk = packpair(hnew, tau);
                unsigned long long* w = rec + slotoff + e0 + lane;
#pragma unroll
                for (int r = 0; r < NREP; ++r)
                    __hip_atomic_store(w + (size_t)r * RSTR, pk,
                                       __ATOMIC_RELAXED, __HIP_MEMORY_SCOPE_AGENT);
            }
        } else if (lane < 4) { // layer 1, element e0+(lane&1), step tau-1
            const int e = e0 + (lane & 1);
            float hnew;
            if (tau >= 1) {
                const float rg = sigm(sred[3] + sred[6] + b_r);
                const float zg = sigm(sred[4] + sred[7] + b_z);
                const float ng = tanha(sred[5] + b_n1 + rg * (sred[8] + b_n2));
                hnew = (1.f - zg) * ng + zg * h1p;
                if (ys) ys[(size_t)(tau - 1) * Hh + e] = hnew;
            } else {
                hnew = h1p;   // pass initial h1 through as "h1(-1)"
            }
            const unsigned long long pk = packpair(hnew, tau);
            unsigned long long* w = rec + slotoff + Hh + e;
#pragma unroll
            for (int r = 0; r < NREP; ++r)
                __hip_atomic_store(w + (size_t)r * RSTR, pk,
                                   __ATOMIC_RELAXED, __HIP_MEMORY_SCOPE_AGENT);
        }

        xr = nxr; xz = nxz; xn = nxn;
    }
}

// ---------------------------------------------------------------------------
// WoutT + encoder record init, all replicas (slot1: h=0 tag=-1; slot0: tag=-2)
// ---------------------------------------------------------------------------
__global__ __launch_bounds__(256) void transposeW(const float* __restrict__ W,
                                                  float* __restrict__ WT,
                                                  unsigned long long* __restrict__ encr)
{
    const int i = blockIdx.x * 256 + threadIdx.x;  // 0..65535
    WT[(i & 511) * 128 + (i >> 9)] = W[i];
    if (i < NPAIR) {
#pragma unroll
        for (int r = 0; r < NREP; ++r) {
            __hip_atomic_store(encr + (size_t)r * RSTR + NPAIR + i, packpair(0.f, -1),
                               __ATOMIC_RELAXED, __HIP_MEMORY_SCOPE_AGENT);
            __hip_atomic_store(encr + (size_t)r * RSTR + i, packpair(0.f, -2),
                               __ATOMIC_RELAXED, __HIP_MEMORY_SCOPE_AGENT);
        }
    }
}

// ---------------------------------------------------------------------------
// encoder -> decoder handoff. enc h0(L-1): slot1 pairs [0..511] (tick L-1);
// enc h1(L-1): slot0 pairs [512..1023] (tick L). Read replica 0, write all
// decoder replicas: slot1 tag=-1 with value, slot0 tag=-2.
// ---------------------------------------------------------------------------
__global__ __launch_bounds__(256) void handoff(const unsigned long long* __restrict__ encr,
                                               unsigned long long* __restrict__ decr)
{
    const int p = blockIdx.x * 256 + threadIdx.x;  // 0..1023
    const unsigned long long src = __hip_atomic_load(
        encr + (p < Hh ? NPAIR : 0) + p, __ATOMIC_RELAXED, __HIP_MEMORY_SCOPE_AGENT);
#pragma unroll
    for (int r = 0; r < NREP; ++r) {
        __hip_atomic_store(decr + (size_t)r * RSTR + NPAIR + p, packpair(pair_val(src), -1),
                           __ATOMIC_RELAXED, __HIP_MEMORY_SCOPE_AGENT);
        __hip_atomic_store(decr + (size_t)r * RSTR + p, packpair(0.f, -2),
                           __ATOMIC_RELAXED, __HIP_MEMORY_SCOPE_AGENT);
    }
}

// ---------------------------------------------------------------------------
// out = sigmoid(ys @ Wout^T + bout)
// ---------------------------------------------------------------------------
__global__ __launch_bounds__(128) void out_proj(
    const float* __restrict__ ys, const float* __restrict__ WT,
    const float* __restrict__ bout, float* __restrict__ out)
{
    __shared__ float yss[16][512];
    const int tid = threadIdx.x;
    const int m0  = blockIdx.x * 16;

    for (int i = tid; i < 16 * 512; i += 128)
        yss[i >> 9][i & 511] = ys[(size_t)(m0 + (i >> 9)) * 512 + (i & 511)];
    __syncthreads();

    const int c = tid;  // 0..127
    float acc[16];
    const float b = bout[c];
#pragma unroll
    for (int m = 0; m < 16; ++m) acc[m] = b;

    for (int k4 = 0; k4 < 128; ++k4) {
        const float w0 = WT[(4 * k4 + 0) * 128 + c];
        const float w1 = WT[(4 * k4 + 1) * 128 + c];
        const float w2 = WT[(4 * k4 + 2) * 128 + c];
        const float w3 = WT[(4 * k4 + 3) * 128 + c];
#pragma unroll
        for (int m = 0; m < 16; ++m) {
            const float4 yv = *(const float4*)&yss[m][4 * k4];
            acc[m] = fmaf(w0, yv.x, fmaf(w1, yv.y, fmaf(w2, yv.z, fmaf(w3, yv.w, acc[m]))));
        }
    }
#pragma unroll
    for (int m = 0; m < 16; ++m)
        out[(size_t)(m0 + m) * 128 + c] = 1.f / (1.f + __expf(-acc[m]));
}

// ---------------------------------------------------------------------------
extern "C" void kernel_launch(void* const* d_in, const int* in_sizes, int n_in,
                              void* d_out, int out_size, void* d_ws, size_t ws_size,
                              hipStream_t stream)
{
    const float* src      = (const float*)d_in[0];
    const float* trg      = (const float*)d_in[1];
    const float* eWih0    = (const float*)d_in[2];
    const float* eWhh0    = (const float*)d_in[3];
    const float* ebih0    = (const float*)d_in[4];
    const float* ebhh0    = (const float*)d_in[5];
    const float* eWih1    = (const float*)d_in[6];
    const float* eWhh1    = (const float*)d_in[7];
    const float* ebih1    = (const float*)d_in[8];
    const float* ebhh1    = (const float*)d_in[9];
    const float* dWih0    = (const float*)d_in[10];
    const float* dWhh0    = (const float*)d_in[11];
    const float* dbih0    = (const float*)d_in[12];
    const float* dbhh0    = (const float*)d_in[13];
    const float* dWih1    = (const float*)d_in[14];
    const float* dWhh1    = (const float*)d_in[15];
    const float* dbih1    = (const float*)d_in[16];
    const float* dbhh1    = (const float*)d_in[17];
    const float* Wout     = (const float*)d_in[18];
    const float* bout     = (const float*)d_in[19];

    char* ws = (char*)d_ws;
    float*              gx   = (float*)(ws + OFF_GX);
    float*              ys   = (float*)(ws + OFF_YS);
    unsigned long long* recE = (unsigned long long*)(ws + OFF_RECE);
    unsigned long long* recD = (unsigned long long*)(ws + OFF_RECD);
    float*              WT   = (float*)(ws + OFF_WT);

    hipLaunchKernelGGL(transposeW, dim3(256), dim3(256), 0, stream, Wout, WT, recE);

    // ---- encoder ----
    hipLaunchKernelGGL(gemm_gx, dim3(LL / 16, 6), dim3(256), 0, stream,
                       src, eWih0, ebih0, gx, 0);
    hipLaunchKernelGGL(seq2, dim3(NBK), dim3(64), 0, stream,
                       gx, eWhh0, eWih1, eWhh1, ebhh0, ebih1, ebhh1,
                       recE, (float*)nullptr);

    // ---- handoff + decoder ----
    hipLaunchKernelGGL(handoff, dim3(4), dim3(256), 0, stream, recE, recD);
    hipLaunchKernelGGL(gemm_gx, dim3(LL / 16, 6), dim3(256), 0, stream,
                       trg, dWih0, dbih0, gx, 1);
    hipLaunchKernelGGL(seq2, dim3(NBK), dim3(64), 0, stream,
                       gx, dWhh0, dWih1, dWhh1, dbhh0, dbih1, dbhh1,
                       recD, ys);

    // ---- output projection ----
    hipLaunchKernelGGL(out_proj, dim3(LL / 16), dim3(128), 0, stream,
                       ys, WT, bout, (float*)d_out);

    (void)in_sizes; (void)n_in; (void)out_size; (void)ws_size;
}

// Round 10
// 32248.669 us; speedup vs baseline: 1.5935x; 1.0632x over previous
//
#include <hip/hip_runtime.h>

// Problem constants
#define Hh   512
#define Vv   128
#define LL   8192
#define G3   1536      // 3*H
#define NBK  256       // 128 layer-0 blocks + 128 layer-1 blocks, 64 thr each
#define S0   16        // h0 ring slots (watermark-gated, 8-tick amortized)
#define S1   4         // h1 ring slots (self-bounded skew <= 2)

// workspace layout (bytes). record = h0ring(16*512 pairs) ++ h1ring(4*512)
#define RECBYTES ((S0*512 + S1*512) * 8ull)            // 81,920
#define OFF_GX   0ull                                  // 50,331,648
#define OFF_YS   50331648ull                           // 16,777,216
#define OFF_RECE 67108864ull
#define OFF_RECD (OFF_RECE + RECBYTES)
#define OFF_WT   (OFF_RECD + RECBYTES)                 // 262,144

#define H1OFF (S0*512)   // pair offset of h1 ring within a record

__device__ __forceinline__ float sigm(float x)  { return 1.f / (1.f + __expf(-x)); }
__device__ __forceinline__ float tanha(float x) { return 2.f / (1.f + __expf(-2.f * x)) - 1.f; }

__device__ __forceinline__ unsigned long long packpair(float v, int t) {
    return ((unsigned long long)(unsigned)t << 32) | (unsigned long long)__float_as_uint(v);
}
__device__ __forceinline__ int   pair_tag(unsigned long long p) { return (int)(p >> 32); }
__device__ __forceinline__ float pair_val(unsigned long long p) { return __uint_as_float((unsigned)p); }

template <int CTRL>
__device__ __forceinline__ float dpp_add(float m) {
    int t = __builtin_amdgcn_update_dpp(0, __builtin_bit_cast(int, m), CTRL, 0xF, 0xF, true);
    return m + __builtin_bit_cast(float, t);
}
// pair-merged butterfly: returns row-2k sum on even lanes / row-2k+1 on odd
__device__ __forceinline__ float red2(float a, float c, int lane) {
    a = dpp_add<0xB1>(a);
    c = dpp_add<0xB1>(c);
    float m = (lane & 1) ? c : a;
    m = dpp_add<0x122>(m);
    m = dpp_add<0x124>(m);
    m = dpp_add<0x128>(m);
    m += __shfl_xor(m, 16);
    m += __shfl_xor(m, 32);
    return m;
}

// ---------------------------------------------------------------------------
// gx = X @ Wih^T + bih
// ---------------------------------------------------------------------------
__global__ __launch_bounds__(256) void gemm_gx(
    const float* __restrict__ X, const float* __restrict__ Wih,
    const float* __restrict__ bih, float* __restrict__ gxo, int shift_relu)
{
    __shared__ float xs[16][128];
    const int tid = threadIdx.x;
    const int m0  = blockIdx.x * 16;
    const int c   = blockIdx.y * 256 + tid;

    for (int i = tid; i < 16 * 128; i += 256) {
        const int r = i >> 7, k = i & 127;
        int srow = m0 + r;
        if (shift_relu) srow = (srow == 0) ? 0 : (srow - 1);
        float v = X[(size_t)srow * Vv + k];
        if (shift_relu) v = fmaxf(v, 0.f);
        xs[r][k] = v;
    }
    __syncthreads();

    const float4* wp = (const float4*)(Wih + (size_t)c * Vv);
    float4 wr[32];
#pragma unroll
    for (int q = 0; q < 32; ++q) wr[q] = wp[q];
    const float bb = bih[c];

    for (int m = 0; m < 16; ++m) {
        const float4* xp = (const float4*)xs[m];
        float acc = bb;
#pragma unroll
        for (int q = 0; q < 32; ++q) {
            const float4 x4 = xp[q];
            acc = fmaf(wr[q].x, x4.x, acc); acc = fmaf(wr[q].y, x4.y, acc);
            acc = fmaf(wr[q].z, x4.z, acc); acc = fmaf(wr[q].w, x4.w, acc);
        }
        gxo[(size_t)(m0 + m) * G3 + c] = acc;
    }
}

// ---------------------------------------------------------------------------
// Split-role persistent GRU scan. Blocks 0-127: layer 0 (own h0[4b..4b+3]);
// blocks 128-255: layer 1 (own h1[...]). h0 ring: 16 slots, slot t&15, tag t.
// h1 ring: 4 slots. Layer-0 tick t: poll h0(t-1) [8 loads/lane], every 8th
// tick verify layer-1 watermark (h1 slot t&3 tag >= t-4; covers publishes
// t..t+7 destroying slots >= 9 ticks old), compute c0(t), publish. Layer-1
// tick t: poll h0(t) + h1(t-1) [h1 a tick old -> usually instant], compute
// c1(t), publish + ys. All pairs self-validating; rings provably safe under
// the watermark (layer-1 ticks >= t-3 when layer-0 publishes t..t+7).
// ---------------------------------------------------------------------------
__global__ __launch_bounds__(64, 1) void seq2(
    const float* __restrict__ gx,
    const float* __restrict__ Whh0, const float* __restrict__ Wih1,
    const float* __restrict__ Whh1,
    const float* __restrict__ bhh0, const float* __restrict__ bih1,
    const float* __restrict__ bhh1,
    unsigned long long* __restrict__ rec,
    float* __restrict__ ys)
{
    const int bid = blockIdx.x, lane = threadIdx.x;
    unsigned long long* h0rec = rec;
    unsigned long long* h1rec = rec + H1OFF;

    if (bid < 128) {
        // ================= layer 0 =================
        const int e0 = 4 * bid;
        int off[8];
#pragma unroll
        for (int j = 0; j < 8; ++j) off[j] = (e0 + lane + 64 * j) & 511;

        float w[12][8];   // rows r = 4*g + i  (Whh0)
#pragma unroll
        for (int g = 0; g < 3; ++g)
#pragma unroll
            for (int i = 0; i < 4; ++i) {
                const float* row = Whh0 + (size_t)(g * Hh + e0 + i) * Hh;
#pragma unroll
                for (int j = 0; j < 8; ++j) w[g * 4 + i][j] = row[off[j]];
            }

        float b_r = 0.f, b_z = 0.f, b_n = 0.f;
        if (lane < 4) {
            const int e = e0 + lane;
            b_r = bhh0[e]; b_z = bhh0[Hh + e]; b_n = bhh0[2 * Hh + e];
        }
        float xr = 0.f, xz = 0.f, xn = 0.f;
        if (lane < 4) {
            xr = gx[e0 + lane]; xz = gx[Hh + e0 + lane]; xn = gx[2 * Hh + e0 + lane];
        }

        for (int t = 0; t < LL; ++t) {
            // spin on h0(t-1)
            const int need = t - 1;
            const unsigned long long* rp = h0rec + (size_t)((t + S0 - 1) & (S0 - 1)) * 512;
            unsigned long long p[8];
            int ok;
            do {
#pragma unroll
                for (int j = 0; j < 8; ++j)
                    p[j] = __hip_atomic_load(rp + off[j], __ATOMIC_RELAXED, __HIP_MEMORY_SCOPE_AGENT);
                ok = 1;
#pragma unroll
                for (int j = 0; j < 8; ++j) ok &= (pair_tag(p[j]) >= need);
            } while (!__all(ok));

            // layer-1 watermark gate, once per 8 ticks (4-tick slack)
            if ((t & 7) == 0) {
                const int gneed = t - 4;
                const unsigned long long* gp = h1rec + (size_t)(t & (S1 - 1)) * 512;
                int gok;
                do {
                    gok = 1;
#pragma unroll
                    for (int j = 0; j < 8; ++j) {
                        const unsigned long long q = __hip_atomic_load(
                            gp + ((lane + 64 * j) & 511), __ATOMIC_RELAXED, __HIP_MEMORY_SCOPE_AGENT);
                        gok &= (pair_tag(q) >= gneed);
                    }
                } while (!__all(gok));
            }

            // prefetch next gx row (hides under next spin)
            float nxr = 0.f, nxz = 0.f, nxn = 0.f;
            if (lane < 4 && t + 1 < LL) {
                const size_t gb = (size_t)(t + 1) * G3 + e0 + lane;
                nxr = gx[gb]; nxz = gx[gb + Hh]; nxn = gx[gb + 2 * Hh];
            }

            float h0v[8];
#pragma unroll
            for (int j = 0; j < 8; ++j) h0v[j] = pair_val(p[j]);

            float acc[12];
#pragma unroll
            for (int r = 0; r < 12; ++r) acc[r] = 0.f;
#pragma unroll
            for (int j = 0; j < 8; ++j)
#pragma unroll
                for (int r = 0; r < 12; ++r) acc[r] = fmaf(w[r][j], h0v[j], acc[r]);

            float sred[6];
#pragma unroll
            for (int k = 0; k < 6; ++k) sred[k] = red2(acc[2 * k], acc[2 * k + 1], lane);

            if (lane < 4) {
                const int i2 = lane >> 1;
                const float rg = sigm(xr + sred[i2] + b_r);
                const float zg = sigm(xz + sred[2 + i2] + b_z);
                const float ng = tanha(xn + rg * (sred[4 + i2] + b_n));
                const float hnew = (1.f - zg) * ng + zg * h0v[0];
                __hip_atomic_store(h0rec + (size_t)(t & (S0 - 1)) * 512 + e0 + lane,
                                   packpair(hnew, t), __ATOMIC_RELAXED, __HIP_MEMORY_SCOPE_AGENT);
            }
            xr = nxr; xz = nxz; xn = nxn;
        }
    } else {
        // ================= layer 1 =================
        const int e0 = 4 * (bid - 128);
        int off[8];
#pragma unroll
        for (int j = 0; j < 8; ++j) off[j] = (e0 + lane + 64 * j) & 511;

        float wA[12][8], wB[12][8];   // Wih1, Whh1; rows r = 4*g + i
#pragma unroll
        for (int g = 0; g < 3; ++g)
#pragma unroll
            for (int i = 0; i < 4; ++i) {
                const float* rowA = Wih1 + (size_t)(g * Hh + e0 + i) * Hh;
                const float* rowB = Whh1 + (size_t)(g * Hh + e0 + i) * Hh;
#pragma unroll
                for (int j = 0; j < 8; ++j) {
                    wA[g * 4 + i][j] = rowA[off[j]];
                    wB[g * 4 + i][j] = rowB[off[j]];
                }
            }

        float b_r = 0.f, b_z = 0.f, b_n1 = 0.f, b_n2 = 0.f;
        if (lane < 4) {
            const int e = e0 + lane;
            b_r  = bih1[e] + bhh1[e];
            b_z  = bih1[Hh + e] + bhh1[Hh + e];
            b_n1 = bih1[2 * Hh + e];
            b_n2 = bhh1[2 * Hh + e];
        }

        for (int t = 0; t < LL; ++t) {
            // poll h0(t) (fresh -> the real wait) + h1(t-1) (a tick old)
            const unsigned long long* rp0 = h0rec + (size_t)(t & (S0 - 1)) * 512;
            const unsigned long long* rp1 = h1rec + (size_t)((t + S1 - 1) & (S1 - 1)) * 512;
            unsigned long long p0[8], p1[8];
            int ok;
            do {
#pragma unroll
                for (int j = 0; j < 8; ++j)
                    p0[j] = __hip_atomic_load(rp0 + off[j], __ATOMIC_RELAXED, __HIP_MEMORY_SCOPE_AGENT);
#pragma unroll
                for (int j = 0; j < 8; ++j)
                    p1[j] = __hip_atomic_load(rp1 + off[j], __ATOMIC_RELAXED, __HIP_MEMORY_SCOPE_AGENT);
                ok = 1;
#pragma unroll
                for (int j = 0; j < 8; ++j)
                    ok &= (pair_tag(p0[j]) >= t) & (pair_tag(p1[j]) >= t - 1);
            } while (!__all(ok));

            float h0v[8], h1v[8];
#pragma unroll
            for (int j = 0; j < 8; ++j) { h0v[j] = pair_val(p0[j]); h1v[j] = pair_val(p1[j]); }

            // acc[0..3] r-gate (A+B), [4..7] z (A+B), [8..11] nA, [12..15] nB
            float acc[16];
#pragma unroll
            for (int r = 0; r < 16; ++r) acc[r] = 0.f;
#pragma unroll
            for (int j = 0; j < 8; ++j) {
#pragma unroll
                for (int r = 0; r < 8; ++r) {
                    acc[r] = fmaf(wA[r][j], h0v[j], acc[r]);
                    acc[r] = fmaf(wB[r][j], h1v[j], acc[r]);
                }
#pragma unroll
                for (int i = 0; i < 4; ++i) {
                    acc[8 + i]  = fmaf(wA[8 + i][j], h0v[j], acc[8 + i]);
                    acc[12 + i] = fmaf(wB[8 + i][j], h1v[j], acc[12 + i]);
                }
            }

            float sred[8];
#pragma unroll
            for (int k = 0; k < 8; ++k) sred[k] = red2(acc[2 * k], acc[2 * k + 1], lane);

            if (lane < 4) {
                const int i2 = lane >> 1;
                const float rg = sigm(sred[i2] + b_r);
                const float zg = sigm(sred[2 + i2] + b_z);
                const float ng = tanha(sred[4 + i2] + b_n1 + rg * (sred[6 + i2] + b_n2));
                const float hnew = (1.f - zg) * ng + zg * h1v[0];
                if (ys) ys[(size_t)t * Hh + e0 + lane] = hnew;
                __hip_atomic_store(h1rec + (size_t)(t & (S1 - 1)) * 512 + e0 + lane,
                                   packpair(hnew, t), __ATOMIC_RELAXED, __HIP_MEMORY_SCOPE_AGENT);
            }
        }
    }
}

// ---------------------------------------------------------------------------
// WoutT + encoder record init. h0 ring: slot 15 = (0, tag -1), others tag
// -100. h1 ring: slot 3 = (0, tag -1), slots 0..2 = tags -4,-3,-2.
// ---------------------------------------------------------------------------
__global__ __launch_bounds__(256) void transposeW(const float* __restrict__ W,
                                                  float* __restrict__ WT,
                                                  unsigned long long* __restrict__ encr)
{
    const int i = blockIdx.x * 256 + threadIdx.x;  // 0..65535
    WT[(i & 511) * 128 + (i >> 9)] = W[i];
    if (i < S0 * 512) {
        const int slot = i >> 9;
        __hip_atomic_store(encr + i, packpair(0.f, (slot == S0 - 1) ? -1 : -100),
                           __ATOMIC_RELAXED, __HIP_MEMORY_SCOPE_AGENT);
    }
    if (i < S1 * 512) {
        const int slot = i >> 9;
        __hip_atomic_store(encr + H1OFF + i, packpair(0.f, (slot == S1 - 1) ? -1 : slot - 4),
                           __ATOMIC_RELAXED, __HIP_MEMORY_SCOPE_AGENT);
    }
}

// ---------------------------------------------------------------------------
// encoder -> decoder handoff. enc h0(8191) is in h0 slot 8191&15 = 15; enc
// h1(8191) in h1 slot 3. Rewrite EVERY decoder slot (stale tags from prior
// replay must die): h0 slot15 = (enc val, -1), others -100; h1 slot3 =
// (enc val, -1), slots 0..2 tags -4,-3,-2.
// ---------------------------------------------------------------------------
__global__ __launch_bounds__(256) void handoff(const unsigned long long* __restrict__ encr,
                                               unsigned long long* __restrict__ decr)
{
    const int p = blockIdx.x * 256 + threadIdx.x;  // 0..8191
    {
        const int slot = p >> 9;
        unsigned long long v;
        if (slot == S0 - 1) {
            const unsigned long long src = __hip_atomic_load(
                encr + p, __ATOMIC_RELAXED, __HIP_MEMORY_SCOPE_AGENT);
            v = packpair(pair_val(src), -1);
        } else {
            v = packpair(0.f, -100);
        }
        __hip_atomic_store(decr + p, v, __ATOMIC_RELAXED, __HIP_MEMORY_SCOPE_AGENT);
    }
    if (p < S1 * 512) {
        const int slot = p >> 9;
        unsigned long long v;
        if (slot == S1 - 1) {
            const unsigned long long src = __hip_atomic_load(
                encr + H1OFF + p, __ATOMIC_RELAXED, __HIP_MEMORY_SCOPE_AGENT);
            v = packpair(pair_val(src), -1);
        } else {
            v = packpair(0.f, slot - 4);
        }
        __hip_atomic_store(decr + H1OFF + p, v, __ATOMIC_RELAXED, __HIP_MEMORY_SCOPE_AGENT);
    }
}

// ---------------------------------------------------------------------------
// out = sigmoid(ys @ Wout^T + bout)
// ---------------------------------------------------------------------------
__global__ __launch_bounds__(128) void out_proj(
    const float* __restrict__ ys, const float* __restrict__ WT,
    const float* __restrict__ bout, float* __restrict__ out)
{
    __shared__ float yss[16][512];
    const int tid = threadIdx.x;
    const int m0  = blockIdx.x * 16;

    for (int i = tid; i < 16 * 512; i += 128)
        yss[i >> 9][i & 511] = ys[(size_t)(m0 + (i >> 9)) * 512 + (i & 511)];
    __syncthreads();

    const int c = tid;
    float acc[16];
    const float b = bout[c];
#pragma unroll
    for (int m = 0; m < 16; ++m) acc[m] = b;

    for (int k4 = 0; k4 < 128; ++k4) {
        const float w0 = WT[(4 * k4 + 0) * 128 + c];
        const float w1 = WT[(4 * k4 + 1) * 128 + c];
        const float w2 = WT[(4 * k4 + 2) * 128 + c];
        const float w3 = WT[(4 * k4 + 3) * 128 + c];
#pragma unroll
        for (int m = 0; m < 16; ++m) {
            const float4 yv = *(const float4*)&yss[m][4 * k4];
            acc[m] = fmaf(w0, yv.x, fmaf(w1, yv.y, fmaf(w2, yv.z, fmaf(w3, yv.w, acc[m]))));
        }
    }
#pragma unroll
    for (int m = 0; m < 16; ++m)
        out[(size_t)(m0 + m) * 128 + c] = 1.f / (1.f + __expf(-acc[m]));
}

// ---------------------------------------------------------------------------
extern "C" void kernel_launch(void* const* d_in, const int* in_sizes, int n_in,
                              void* d_out, int out_size, void* d_ws, size_t ws_size,
                              hipStream_t stream)
{
    const float* src      = (const float*)d_in[0];
    const float* trg      = (const float*)d_in[1];
    const float* eWih0    = (const float*)d_in[2];
    const float* eWhh0    = (const float*)d_in[3];
    const float* ebih0    = (const float*)d_in[4];
    const float* ebhh0    = (const float*)d_in[5];
    const float* eWih1    = (const float*)d_in[6];
    const float* eWhh1    = (const float*)d_in[7];
    const float* ebih1    = (const float*)d_in[8];
    const float* ebhh1    = (const float*)d_in[9];
    const float* dWih0    = (const float*)d_in[10];
    const float* dWhh0    = (const float*)d_in[11];
    const float* dbih0    = (const float*)d_in[12];
    const float* dbhh0    = (const float*)d_in[13];
    const float* dWih1    = (const float*)d_in[14];
    const float* dWhh1    = (const float*)d_in[15];
    const float* dbih1    = (const float*)d_in[16];
    const float* dbhh1    = (const float*)d_in[17];
    const float* Wout     = (const float*)d_in[18];
    const float* bout     = (const float*)d_in[19];

    char* ws = (char*)d_ws;
    float*              gx   = (float*)(ws + OFF_GX);
    float*              ys   = (float*)(ws + OFF_YS);
    unsigned long long* recE = (unsigned long long*)(ws + OFF_RECE);
    unsigned long long* recD = (unsigned long long*)(ws + OFF_RECD);
    float*              WT   = (float*)(ws + OFF_WT);

    hipLaunchKernelGGL(transposeW, dim3(256), dim3(256), 0, stream, Wout, WT, recE);

    // ---- encoder ----
    hipLaunchKernelGGL(gemm_gx, dim3(LL / 16, 6), dim3(256), 0, stream,
                       src, eWih0, ebih0, gx, 0);
    hipLaunchKernelGGL(seq2, dim3(NBK), dim3(64), 0, stream,
                       gx, eWhh0, eWih1, eWhh1, ebhh0, ebih1, ebhh1,
                       recE, (float*)nullptr);

    // ---- handoff + decoder ----
    hipLaunchKernelGGL(handoff, dim3(32), dim3(256), 0, stream, recE, recD);
    hipLaunchKernelGGL(gemm_gx, dim3(LL / 16, 6), dim3(256), 0, stream,
                       trg, dWih0, dbih0, gx, 1);
    hipLaunchKernelGGL(seq2, dim3(NBK), dim3(64), 0, stream,
                       gx, dWhh0, dWih1, dWhh1, dbhh0, dbih1, dbhh1,
                       recD, ys);

    // ---- output projection ----
    hipLaunchKernelGGL(out_proj, dim3(LL / 16), dim3(128), 0, stream,
                       ys, WT, bout, (float*)d_out);

    (void)in_sizes; (void)n_in; (void)out_size; (void)ws_size;
}